// Round 8
// baseline (238.963 us; speedup 1.0000x reference)
//
#include <hip/hip_runtime.h>

// Mandelbrot counts — R6-proven bit-exact arithmetic + compaction + wave-
// aggregated enqueue (R8) + strip-mined recursive compaction (R11/R12) +
// packed fp32 4px/lane fused body (R14), combined (R16).
//
// R15 post-mortem: hipLaunchCooperativeKernel is REJECTED under hip-graph
// stream capture -> empty graph -> out stayed memset-zero (absmax=256 = max
// ref value). Cooperative/grid-sync approaches are off the table for this
// harness. Reverted.
//
// R16 rationale (from R12 vs R14 A/B): R12 (5 dispatches, 2px strips)=234.8
// beat R14 (3 dispatches, 4px fixed-240 B)=237.6 with the same stage A ->
// dispatch gaps are small (<~5us) and the two wins are INDEPENDENT and never
// combined: strip ladder cuts B px-checks 461M->~205M; the 4px fused body
// cuts per-check issue ~30% vs 2px. R16 = R14 stage A + 4px strip ladder.
// zero_ctrs kernel replaced by hipMemsetAsync(ws,0,4096) (graph-legal).
//
// Proven bit-exact sequence per check (absmax=0 lineage R6..R14):
//   zi2=fl(zi*zi); mag=fma(zr,zr,zi2); t=fma(zr,zr,-zi2)  [VOP3P neg mod]
//   zr'=fl(t+cr); t2=fl(zr+zr); zi'=fma(t2,zi,ci)
//   act=(mag<4)?act:0 (sticky, NaN-safe); cnt+=act (exact small-int add)
// Cardioid/bulb shortcut margin 1e-3 (HW-validated).
//
// Ladder: A: checks 0..15 (all px) -> q0 | B1: 16..55 q0->q1 |
// B2: 56..135 q1->q0 storage | B3: 136..255 finish.
// d_ws: [0,4096) 64 lines x 64B; line s dwords +0=q0 cnt, +4=q1 cnt,
// +8=q2 cnt. q0 recs @4096, q1 after. Overflow at any enqueue -> finish
// inline (correct, slower). ws too small for 2 queues -> single-queue
// fixed-240 path; tiny ws -> monolithic fallback.

#define MAX_ITERS 256

typedef __attribute__((ext_vector_type(2))) float f32x2;
typedef __attribute__((ext_vector_type(4))) float f32x4;

// ---------- scalar proven body (fallback + overflow inline) ----------
__device__ __forceinline__ float mul32(float a, float b) {
    float d; asm("v_mul_f32 %0, %1, %2" : "=v"(d) : "v"(a), "v"(b)); return d;
}
__device__ __forceinline__ float add32(float a, float b) {
    float d; asm("v_add_f32 %0, %1, %2" : "=v"(d) : "v"(a), "v"(b)); return d;
}
__device__ __forceinline__ float fma32(float a, float b, float c) {
    float d; asm("v_fma_f32 %0, %1, %2, %3" : "=v"(d) : "v"(a), "v"(b), "v"(c)); return d;
}
__device__ __forceinline__ float fma32_negc(float a, float b, float c) {
    float d; asm("v_fma_f32 %0, %1, %2, -%3" : "=v"(d) : "v"(a), "v"(b), "v"(c)); return d;
}

__device__ __forceinline__ void iter_checks(float cr, float ci,
                                            float& zr, float& zi,
                                            float& act, float& cnt, int nchecks)
{
    #pragma unroll 8
    for (int s = 0; s < nchecks; ++s) {
        const float zi2 = mul32(zi, zi);
        const float mag = fma32(zr, zr, zi2);
        act = (mag < 4.0f) ? act : 0.0f;
        cnt = cnt + act;
        const float t   = fma32_negc(zr, zr, zi2);
        const float nr  = add32(t, cr);
        const float t2  = add32(zr, zr);
        zi = fma32(t2, zi, ci);
        zr = nr;
    }
}

// ---------- fused packed z-step: exactly 6 v_pk ops, mag out ----------
__device__ __forceinline__ void zstep2(const f32x2 cr, const f32x2 ci,
                                       f32x2& zr, f32x2& zi, f32x2& mag)
{
    f32x2 s, t, u;
    asm("v_pk_mul_f32 %0, %5, %5\n\t"                                   // s   = zi*zi
        "v_pk_fma_f32 %1, %4, %4, %0\n\t"                               // mag = zr*zr + s
        "v_pk_fma_f32 %2, %4, %4, %0 neg_lo:[0,0,1] neg_hi:[0,0,1]\n\t" // t = zr*zr - s
        "v_pk_add_f32 %3, %4, %4\n\t"                                   // u   = zr + zr
        "v_pk_add_f32 %4, %2, %6\n\t"                                   // zr' = t + cr
        "v_pk_fma_f32 %5, %3, %5, %7"                                   // zi' = u*zi + ci
        : "=&v"(s), "=&v"(mag), "=&v"(t), "=&v"(u), "+v"(zr), "+v"(zi)
        : "v"(cr), "v"(ci));
}

// One check over 4 pixels (two streams). Bookkeeping is the PROVEN C form.
__device__ __forceinline__ void check4(
    const f32x2 crA, const f32x2 ciA, f32x2& zrA, f32x2& ziA,
    const f32x2 crB, const f32x2 ciB, f32x2& zrB, f32x2& ziB,
    float& act0, float& act1, float& act2, float& act3,
    float& cnt0, float& cnt1, float& cnt2, float& cnt3)
{
    f32x2 magA, magB;
    zstep2(crA, ciA, zrA, ziA, magA);
    zstep2(crB, ciB, zrB, ziB, magB);
    act0 = (magA.x < 4.0f) ? act0 : 0.0f;  cnt0 += act0;
    act1 = (magA.y < 4.0f) ? act1 : 0.0f;  cnt1 += act1;
    act2 = (magB.x < 4.0f) ? act2 : 0.0f;  cnt2 += act2;
    act3 = (magB.y < 4.0f) ? act3 : 0.0f;  cnt3 += act3;
}

__device__ __forceinline__ int lane_id() {
    return __builtin_amdgcn_mbcnt_hi(~0u, __builtin_amdgcn_mbcnt_lo(~0u, 0));
}

__device__ __forceinline__ bool in_shortcut(float cr, float ci) {
    const float xq = cr - 0.25f;
    const float q  = xq * xq + ci * ci;
    const bool in_card = (q * (q + xq) - 0.25f * ci * ci) < -1e-3f;
    const float xb = cr + 1.0f;
    const bool in_bulb = (xb * xb + ci * ci) < (0.0625f - 1e-3f);
    return in_card | in_bulb;
}

// ---------- stage A body: 16 checks on one quad, enqueue to q0 ----------
__device__ __forceinline__ void phaseA_quad(
    const float* __restrict__ c_real, const float* __restrict__ c_imag,
    float* __restrict__ out, unsigned char* __restrict__ ws,
    unsigned seg_cap, int n, int p0, int seg)
{
    if (p0 + 3 >= n) {  // ragged tail: finish fully inline, proven scalar
        for (int j = 0; j < 4 && p0 + j < n; ++j) {
            const float cr = c_real[p0 + j], ci = c_imag[p0 + j];
            if (in_shortcut(cr, ci)) { out[p0 + j] = 256.0f; continue; }
            float zr = cr, zi = ci, act = 1.0f, cnt = 0.0f;
            iter_checks(cr, ci, zr, zi, act, cnt, MAX_ITERS);
            out[p0 + j] = cnt;
        }
        return;
    }

    const f32x4 cr4 = *(const f32x4*)(c_real + p0);
    const f32x4 ci4 = *(const f32x4*)(c_imag + p0);
    const f32x2 crA = {cr4.x, cr4.y}, ciA = {ci4.x, ci4.y};
    const f32x2 crB = {cr4.z, cr4.w}, ciB = {ci4.z, ci4.w};
    const bool sc0 = in_shortcut(cr4.x, ci4.x);
    const bool sc1 = in_shortcut(cr4.y, ci4.y);
    const bool sc2 = in_shortcut(cr4.z, ci4.z);
    const bool sc3 = in_shortcut(cr4.w, ci4.w);

    f32x2 zrA = crA, ziA = ciA, zrB = crB, ziB = ciB;
    float act0 = 1.0f, act1 = 1.0f, act2 = 1.0f, act3 = 1.0f;
    float cnt0 = 0.0f, cnt1 = 0.0f, cnt2 = 0.0f, cnt3 = 0.0f;
    #pragma unroll
    for (int s = 0; s < 16; ++s)
        check4(crA, ciA, zrA, ziA, crB, ciB, zrB, ziB,
               act0, act1, act2, act3, cnt0, cnt1, cnt2, cnt3);

    const bool sv0 = (!sc0) && (act0 != 0.0f);
    const bool sv1 = (!sc1) && (act1 != 0.0f);
    const bool sv2 = (!sc2) && (act2 != 0.0f);
    const bool sv3 = (!sc3) && (act3 != 0.0f);

    const unsigned long long m0 = __ballot(sv0);
    const unsigned long long m1 = __ballot(sv1);
    const unsigned long long m2 = __ballot(sv2);
    const unsigned long long m3 = __ballot(sv3);
    const unsigned long long any = m0 | m1 | m2 | m3;
    if (any != 0ull) {
        const int lane = lane_id();
        const int leader = (int)__ffsll(any) - 1;
        unsigned* ctr = (unsigned*)(ws + (size_t)seg * 64u);
        const unsigned c0 = (unsigned)__popcll(m0);
        const unsigned c1 = (unsigned)__popcll(m1);
        const unsigned c2 = (unsigned)__popcll(m2);
        unsigned base = 0u;
        if (lane == leader)
            base = atomicAdd(ctr, c0 + c1 + c2 + (unsigned)__popcll(m3));
        base = (unsigned)__shfl((int)base, leader, 64);
        float4* qf = (float4*)(ws + 4096);
        int*    qi = (int*)(ws + 4096 + (size_t)seg_cap * 64u * 16u);
        const unsigned long long below = (1ull << lane) - 1ull;
        const size_t segbase = (size_t)seg * seg_cap;

        float zrv[4] = {zrA.x, zrA.y, zrB.x, zrB.y};
        float ziv[4] = {ziA.x, ziA.y, ziB.x, ziB.y};
        float crv[4] = {cr4.x, cr4.y, cr4.z, cr4.w};
        float civ[4] = {ci4.x, ci4.y, ci4.z, ci4.w};
        float cnv[4] = {cnt0, cnt1, cnt2, cnt3};
        const bool svv[4] = {sv0, sv1, sv2, sv3};
        const unsigned prev[4] = {0u, c0, c0 + c1, c0 + c1 + c2};
        const unsigned long long mv[4] = {m0, m1, m2, m3};
        #pragma unroll
        for (int j = 0; j < 4; ++j) {
            if (!svv[j]) continue;
            const unsigned slot = base + prev[j] +
                (unsigned)__popcll(mv[j] & below);
            if (slot < seg_cap) {
                qf[segbase + slot] = make_float4(zrv[j], ziv[j], crv[j], civ[j]);
                qi[segbase + slot] = p0 + j;
            } else {   // overflow: finish inline with proven scalar body
                float zrs = zrv[j], zis = ziv[j], as = 1.0f, cs = cnv[j];
                iter_checks(crv[j], civ[j], zrs, zis, as, cs, 240);
                out[p0 + j] = cs;
            }
        }
    }
    if (!sv0) out[p0 + 0] = sc0 ? 256.0f : cnt0;
    if (!sv1) out[p0 + 1] = sc1 ? 256.0f : cnt1;
    if (!sv2) out[p0 + 2] = sc2 ? 256.0f : cnt2;
    if (!sv3) out[p0 + 3] = sc3 ? 256.0f : cnt3;
}

// ---------- strip body: NCHECKS on 4 records/thread, optional requeue ----
template <int NCHECKS, int START, bool HAS_DST>
__device__ __forceinline__ void strip_phase(
    float* __restrict__ out, unsigned char* __restrict__ ws,
    const float4* __restrict__ srcF, const int* __restrict__ srcI,
    float4* __restrict__ dstF, int* __restrict__ dstI,
    int src_ctr, int dst_ctr, unsigned seg_cap,
    int seg, int grp, int blocks_per_seg)
{
    const unsigned cnt_s = __hip_atomic_load(
        (const unsigned*)(ws + (size_t)seg * 64u + (size_t)src_ctr * 4u),
        __ATOMIC_RELAXED, __HIP_MEMORY_SCOPE_AGENT);
    const unsigned nq = (cnt_s < seg_cap) ? cnt_s : seg_cap;
    const unsigned q = (nq + 3u) >> 2;
    const unsigned stride = (unsigned)blocks_per_seg * 256u;
    const size_t segbase = (size_t)seg * seg_cap;
    const int lane = lane_id();

    for (unsigned k = (unsigned)grp * 256u + threadIdx.x; k < q; k += stride) {
        const unsigned i1 = k + q, i2 = k + 2u * q, i3 = k + 3u * q;
        const bool v1 = (i1 < nq), v2 = (i2 < nq), v3 = (i3 < nq);
        const float4 r0 = srcF[segbase + k];
        const float4 r1 = v1 ? srcF[segbase + i1] : r0;
        const float4 r2 = v2 ? srcF[segbase + i2] : r0;
        const float4 r3 = v3 ? srcF[segbase + i3] : r0;
        const int idx0 = srcI[segbase + k];
        const int idx1 = v1 ? srcI[segbase + i1] : -1;
        const int idx2 = v2 ? srcI[segbase + i2] : -1;
        const int idx3 = v3 ? srcI[segbase + i3] : -1;

        f32x2 zrA = {r0.x, r1.x}, ziA = {r0.y, r1.y};
        f32x2 crA = {r0.z, r1.z}, ciA = {r0.w, r1.w};
        f32x2 zrB = {r2.x, r3.x}, ziB = {r2.y, r3.y};
        f32x2 crB = {r2.z, r3.z}, ciB = {r2.w, r3.w};
        float act0 = 1.0f, act1 = v1 ? 1.0f : 0.0f;
        float act2 = v2 ? 1.0f : 0.0f, act3 = v3 ? 1.0f : 0.0f;
        float cnt0 = (float)START, cnt1 = (float)START;
        float cnt2 = (float)START, cnt3 = (float)START;
        #pragma unroll 8
        for (int s = 0; s < NCHECKS; ++s)
            check4(crA, ciA, zrA, ziA, crB, ciB, zrB, ziB,
                   act0, act1, act2, act3, cnt0, cnt1, cnt2, cnt3);

        if (HAS_DST) {
            const bool sv0 = (act0 != 0.0f);
            const bool sv1 = (act1 != 0.0f);   // invalid halves stay dead
            const bool sv2 = (act2 != 0.0f);
            const bool sv3 = (act3 != 0.0f);
            const unsigned long long m0 = __ballot(sv0);
            const unsigned long long m1 = __ballot(sv1);
            const unsigned long long m2 = __ballot(sv2);
            const unsigned long long m3 = __ballot(sv3);
            const unsigned long long any = m0 | m1 | m2 | m3;
            if (any != 0ull) {
                const int leader = (int)__ffsll(any) - 1;
                unsigned* ctr = (unsigned*)(ws + (size_t)seg * 64u
                                               + (size_t)dst_ctr * 4u);
                const unsigned c0 = (unsigned)__popcll(m0);
                const unsigned c1 = (unsigned)__popcll(m1);
                const unsigned c2 = (unsigned)__popcll(m2);
                unsigned base = 0u;
                if (lane == leader)
                    base = atomicAdd(ctr, c0 + c1 + c2 + (unsigned)__popcll(m3));
                base = (unsigned)__shfl((int)base, leader, 64);
                const unsigned long long below = (1ull << lane) - 1ull;

                float zrv[4] = {zrA.x, zrA.y, zrB.x, zrB.y};
                float ziv[4] = {ziA.x, ziA.y, ziB.x, ziB.y};
                float crv[4] = {crA.x, crA.y, crB.x, crB.y};
                float civ[4] = {ciA.x, ciA.y, ciB.x, ciB.y};
                float cnv[4] = {cnt0, cnt1, cnt2, cnt3};
                const int  idxv[4] = {idx0, idx1, idx2, idx3};
                const bool svv[4] = {sv0, sv1, sv2, sv3};
                const unsigned prev[4] = {0u, c0, c0 + c1, c0 + c1 + c2};
                const unsigned long long mv[4] = {m0, m1, m2, m3};
                #pragma unroll
                for (int j = 0; j < 4; ++j) {
                    if (!svv[j]) continue;
                    const unsigned slot = base + prev[j] +
                        (unsigned)__popcll(mv[j] & below);
                    if (slot < seg_cap) {
                        dstF[segbase + slot] =
                            make_float4(zrv[j], ziv[j], crv[j], civ[j]);
                        dstI[segbase + slot] = idxv[j];
                    } else {   // overflow: finish inline (correct, slower)
                        float zrs = zrv[j], zis = ziv[j], as = 1.0f, cs = cnv[j];
                        iter_checks(crv[j], civ[j], zrs, zis, as, cs,
                                    256 - START - NCHECKS);
                        out[idxv[j]] = cs;
                    }
                }
            }
            if (!sv0) out[idx0] = cnt0;          // escaped this strip
            if (v1 && !sv1) out[idx1] = cnt1;
            if (v2 && !sv2) out[idx2] = cnt2;
            if (v3 && !sv3) out[idx3] = cnt3;
        } else {
            out[idx0] = cnt0;                    // final strip
            if (v1) out[idx1] = cnt1;
            if (v2) out[idx2] = cnt2;
            if (v3) out[idx3] = cnt3;
        }
    }
}

// ---------- kernels ----------
__global__ __launch_bounds__(256) void mandel_stage_a_q(
    const float* __restrict__ c_real, const float* __restrict__ c_imag,
    float* __restrict__ out, unsigned char* __restrict__ ws,
    unsigned seg_cap, int n)
{
    const int tq = blockIdx.x * blockDim.x + threadIdx.x;
    const int p0 = tq << 2;
    if (p0 >= n) return;
    phaseA_quad(c_real, c_imag, out, ws, seg_cap, n, p0, blockIdx.x & 63);
}

template <int NCHECKS, int START, bool HAS_DST>
__global__ __launch_bounds__(256) void mandel_strip_q(
    float* __restrict__ out, unsigned char* __restrict__ ws,
    const float4* __restrict__ srcF, const int* __restrict__ srcI,
    float4* __restrict__ dstF, int* __restrict__ dstI,
    int src_ctr, int dst_ctr, unsigned seg_cap, int blocks_per_seg)
{
    strip_phase<NCHECKS, START, HAS_DST>(
        out, ws, srcF, srcI, dstF, dstI, src_ctr, dst_ctr, seg_cap,
        (int)(blockIdx.x & 63u), (int)(blockIdx.x >> 6), blocks_per_seg);
}

__global__ __launch_bounds__(256) void mandel_mono(
    const float* __restrict__ c_real, const float* __restrict__ c_imag,
    float* __restrict__ out, int n)
{
    int i = blockIdx.x * blockDim.x + threadIdx.x;
    if (i >= n) return;
    const float cr = c_real[i], ci = c_imag[i];
    float zr = cr, zi = ci, act = 1.0f, cnt = 0.0f;
    iter_checks(cr, ci, zr, zi, act, cnt, MAX_ITERS);
    out[i] = cnt;
}

extern "C" void kernel_launch(void* const* d_in, const int* in_sizes, int n_in,
                              void* d_out, int out_size, void* d_ws, size_t ws_size,
                              hipStream_t stream)
{
    const float* c_real = (const float*)d_in[0];
    const float* c_imag = (const float*)d_in[1];
    float* out = (float*)d_out;
    const int n = in_sizes[0];  // 4096*4096
    const int block = 256;

    unsigned char* ws = (unsigned char*)d_ws;
    const size_t avail = (ws_size > 4096) ? (ws_size - 4096) : 0;
    const unsigned seg_cap1 = (unsigned)(avail / (64u * 20u));        // 1 queue
    const unsigned seg_cap2 = (unsigned)(avail / (64u * 20u * 2u));   // 2 queues

    if (seg_cap1 < 8192u) {  // ws too small for compaction: proven fallback
        const int gridA = (n + block - 1) / block;
        mandel_mono<<<gridA, block, 0, stream>>>(c_real, c_imag, out, n);
        return;
    }

    // zero the 64 counter lines (graph-legal async memset, no extra kernel)
    hipMemsetAsync(ws, 0, 4096, stream);

    const int nquads = (n + 3) / 4;
    const int gridA = (nquads + block - 1) / block;

    if (seg_cap2 >= 33000u) {
        // 4px strip-mined ladder with ping-pong queues.
        const unsigned sc = seg_cap2;
        float4* q0f = (float4*)(ws + 4096);
        int*    q0i = (int*)(ws + 4096 + (size_t)sc * 64u * 16u);
        float4* q1f = (float4*)(ws + 4096 + (size_t)sc * 64u * 20u);
        int*    q1i = (int*)(ws + 4096 + (size_t)sc * 64u * 20u
                                       + (size_t)sc * 64u * 16u);

        mandel_stage_a_q<<<gridA, block, 0, stream>>>(c_real, c_imag, out,
                                                      ws, sc, n);
        // B1: checks 16..55 (40), q0 -> q1 (ctr 0 -> ctr 1)
        mandel_strip_q<40, 16, true><<<64 * 32, block, 0, stream>>>(
            out, ws, q0f, q0i, q1f, q1i, 0, 1, sc, 32);
        // B2: checks 56..135 (80), q1 -> q0 storage (ctr 1 -> ctr 2)
        mandel_strip_q<80, 56, true><<<64 * 16, block, 0, stream>>>(
            out, ws, q1f, q1i, q0f, q0i, 1, 2, sc, 16);
        // B3: checks 136..255 (120), finish (ctr 2)
        mandel_strip_q<120, 136, false><<<64 * 16, block, 0, stream>>>(
            out, ws, q0f, q0i, (float4*)nullptr, (int*)nullptr, 2, 0, sc, 16);
        return;
    }

    // Single-queue path: stage A + fixed-240 4px stage B (proven R14).
    mandel_stage_a_q<<<gridA, block, 0, stream>>>(c_real, c_imag, out,
                                                  ws, seg_cap1, n);
    mandel_strip_q<240, 16, false><<<64 * 32, block, 0, stream>>>(
        out, ws,
        (const float4*)(ws + 4096),
        (const int*)(ws + 4096 + (size_t)seg_cap1 * 64u * 16u),
        (float4*)nullptr, (int*)nullptr, 0, 0, seg_cap1, 32);
}